// Round 12
// baseline (1482.360 us; speedup 1.0000x reference)
//
#include <hip/hip_runtime.h>
#include <stdint.h>

// ---------------------------------------------------------------------------
// Seq2seq decoder: Luong attention + 2-layer LSTM, B=64, T=48, S=48, E=512,
// H=1024. Round 12: round-11 kernel with the barrier's combiner hop removed:
// quartet-escalation barrier (4th arriver of each 4-block quartet sees
// old==3 from its own fetch_add and escalates with ONE relaxed agent add to
// a single global epoch counter; everyone polls that one line to 64).
// Also: g1p shadow moved to bar1's window (better balance).
// ---------------------------------------------------------------------------

using short8 = __attribute__((ext_vector_type(8))) short;
using f32x4  = __attribute__((ext_vector_type(4))) float;
typedef unsigned short u16;
typedef unsigned long long u64;

#define B_  64
#define T_  48
#define S_  48
#define H_  1024
#define E_  512

__device__ __forceinline__ float bf2f(u16 u) {
    union { unsigned int i; float f; } v; v.i = ((unsigned int)u) << 16; return v.f;
}
__device__ __forceinline__ u16 f2bf(float f) {
    union { float f; unsigned int i; } v; v.f = f;
    unsigned int r = v.i + 0x7fff + ((v.i >> 16) & 1);   // RNE
    return (u16)(r >> 16);
}
__device__ __forceinline__ float sigm(float x) { return 1.f / (1.f + __expf(-x)); }

// ---------------- setup kernels ----------------

__global__ void cast_copy(u16* __restrict__ dst, int dld, int doff,
                          const float* __restrict__ src, int sld, int soff,
                          int rows, int colshift) {
    int cols = 1 << colshift;
    int total = rows << colshift;
    for (int i = blockIdx.x * blockDim.x + threadIdx.x; i < total;
         i += gridDim.x * blockDim.x) {
        int r = i >> colshift, c = i & (cols - 1);
        dst[(size_t)r * dld + doff + c] = f2bf(src[(size_t)r * sld + soff + c]);
    }
}

__global__ void transpose_cast(u16* __restrict__ dst, const float* __restrict__ src) {
    int idx = blockIdx.x * blockDim.x + threadIdx.x;   // 1M threads exactly
    int r = idx >> 10, c = idx & 1023;
    dst[idx] = f2bf(src[(size_t)c * 1024 + r]);
}

__global__ void embed_gather(u16* __restrict__ embA, const float* __restrict__ emb,
                             const int* __restrict__ tgt) {
    int row = blockIdx.x;              // t*64 + b
    int t = row >> 6, b = row & 63;
    int id = tgt[b * T_ + t];
    const float* s = emb + (size_t)id * E_;
    u16* d = embA + (size_t)row * E_;
    for (int e = threadIdx.x; e < E_; e += blockDim.x) d[e] = f2bf(s[e]);
}

__global__ void sbias_kernel(float* __restrict__ sbias, const float* __restrict__ enc,
                             const float* __restrict__ b_l) {
    int r = blockIdx.x, lane = threadIdx.x;
    const float* e = enc + (size_t)r * H_;
    float acc = 0.f;
    for (int k = lane; k < H_; k += 64) acc += b_l[k] * e[k];
    for (int o = 32; o; o >>= 1) acc += __shfl_xor(acc, o);
    if (lane == 0) sbias[r] = acc;
}

__global__ void init_state(u16* __restrict__ xa0_0, u16* __restrict__ xa1_0,
                           const float* __restrict__ h0) {
    int i = blockIdx.x * blockDim.x + threadIdx.x;   // 131072 exactly
    int l = i >> 16, rem = i & 65535, b = rem >> 10, c = rem & 1023;
    u16 hb = f2bf(h0[i]);
    if (l == 0) xa0_0[b * 2048 + 1024 + c] = hb;
    else        xa1_0[b * 2048 + 1024 + c] = hb;
}

// ---------------- setup GEMM: D[M][N] = A[M][K] * W[N][K]^T + bias ----------
__global__ __launch_bounds__(256) void gemm64(
    const u16* __restrict__ A, const u16* __restrict__ W, u16* __restrict__ D,
    const float* __restrict__ bias1, const float* __restrict__ bias2,
    int N, int Kd)
{
    __shared__ float part[4][64][65];
    int tid = threadIdx.x, w = tid >> 6, lane = tid & 63;
    int hf = lane >> 4, q = lane & 15;
    int n0 = blockIdx.x * 64, m0 = blockIdx.y * 64;
    int ks = Kd >> 2;
    int kb = w * ks + hf * 8;
    const u16* ap = A + (size_t)(m0 + q) * Kd + kb;
    const u16* wp = W + (size_t)(n0 + q) * Kd + kb;
    f32x4 acc[4][4] = {};
    for (int k0 = 0; k0 < ks; k0 += 32) {
        short8 bf[4], af[4];
#pragma unroll
        for (int n = 0; n < 4; ++n) bf[n] = *(const short8*)(wp + (size_t)n * 16 * Kd + k0);
#pragma unroll
        for (int m = 0; m < 4; ++m) af[m] = *(const short8*)(ap + (size_t)m * 16 * Kd + k0);
#pragma unroll
        for (int m = 0; m < 4; ++m)
#pragma unroll
            for (int n = 0; n < 4; ++n)
                acc[m][n] = __builtin_amdgcn_mfma_f32_16x16x32_bf16(af[m], bf[n], acc[m][n], 0, 0, 0);
    }
#pragma unroll
    for (int m = 0; m < 4; ++m)
#pragma unroll
        for (int n = 0; n < 4; ++n)
#pragma unroll
            for (int r = 0; r < 4; ++r)
                part[w][m * 16 + hf * 4 + r][n * 16 + q] = acc[m][n][r];
    __syncthreads();
#pragma unroll
    for (int k = 0; k < 16; ++k) {
        int o = tid + k * 256;
        int row = o >> 6, col = o & 63;
        float v = part[0][row][col] + part[1][row][col]
                + part[2][row][col] + part[3][row][col];
        if (bias1) v += bias1[n0 + col] + bias2[n0 + col];
        D[(size_t)(m0 + row) * N + n0 + col] = f2bf(v);
    }
}

// ---------------- persistent decoder kernel ---------------------------------

struct PParams {
    const float *W_ih0, *W_hh0, *W_ih1, *W_hh1;   // f32 weight sources
    const u16  *preG, *encW, *encB;
    const float *sbias, *b_ih1, *b_hh1, *c0in;
    const unsigned char* mask;
    u16 *XA0, *XA1;                               // 49 rotated buffers each
    float *out, *hn0, *hn1, *cn0, *cn1;
    unsigned *cnt, *gcnt;                         // quartet + global epoch cnt
};

// Quartet-escalation barrier (relaxed-only, no wbl2):
//  - arrival: RELAXED agent fetch_add into the quartet counter (4 same-XCD
//    blocks share one). The 4th arriver sees old==3 FROM ITS OWN RMW (no
//    polling) and escalates: one RELAXED agent add to the single global
//    epoch counter.
//  - wait: every block's thread0 polls the single global counter to 64.
// Data freshness: write-through atomic stores + rotated single-writer
// buffers. Timeout valve: wrong answer, never a hang.
__device__ __forceinline__ void gridarrive(unsigned* cnt, unsigned* gcnt,
                                           int ep, int g) {
    __syncthreads();                  // drains vmcnt: exchange stores acked
    if (threadIdx.x == 0) {
        unsigned old = __hip_atomic_fetch_add(&cnt[g * 256 + ep], 1u,
                                              __ATOMIC_RELAXED,
                                              __HIP_MEMORY_SCOPE_AGENT);
        if (old == 3u)
            __hip_atomic_fetch_add(&gcnt[ep * 16], 1u,
                                   __ATOMIC_RELAXED, __HIP_MEMORY_SCOPE_AGENT);
    }
    asm volatile("" ::: "memory");
}
__device__ __forceinline__ void gridpoll(unsigned* gcnt, int ep) {
    if (threadIdx.x == 0) {
        int spin = 0;
        while (__hip_atomic_load(&gcnt[ep * 16], __ATOMIC_RELAXED,
                                 __HIP_MEMORY_SCOPE_AGENT) < 64u) {
            if (++spin > (1 << 20)) break;
        }
    }
    asm volatile("" ::: "memory");
    __syncthreads();
}

__global__ void __launch_bounds__(256, 1) decoder_persistent(PParams P) {
    // 128 KB resident weights: [layer][chunk*16 + qslot][8] bf16.
    __shared__ u16 wlds[2][4096][8];
    __shared__ union {
        struct { float h1f[1056]; float sc[48][4]; float pr[48]; } at;  // padded
        float gates[64][20];   // cols 0..15 gate partials, 16..17 = h-pack
    } sm;

    const int tid = threadIdx.x, blk = blockIdx.x;
    const int w = tid >> 6, lane = tid & 63, g4 = lane >> 4, q = lane & 15;
    const int b2 = tid >> 2, j2 = tid & 3;
    const int colg = blk * 4 + j2;                 // this thread's h-column

    // ---- one-time: fill LDS weight slices (f32 -> bf16, chunked layout) ----
    {
        int r = tid & 15, cb = tid >> 4;
        int grow = (r >> 2) * 1024 + blk * 4 + (r & 3);   // gate row
#pragma unroll
        for (int l = 0; l < 2; ++l) {
            const float* Sa = l ? P.W_ih1 : P.W_ih0;
            const float* Sb = l ? P.W_hh1 : P.W_hh0;
            int sld  = l ? 1024 : 1536;
            int soff = l ? 0 : 512;
            for (int it = 0; it < 16; ++it) {
                int c = cb + it * 16;
                int k = c * 8;
                const float* src = (k < 1024)
                    ? (Sa + (size_t)grow * sld + soff + k)
                    : (Sb + (size_t)grow * 1024 + (k - 1024));
                float4 x0 = *(const float4*)(src);
                float4 x1 = *(const float4*)(src + 4);
                short8 v;
                v[0] = f2bf(x0.x); v[1] = f2bf(x0.y); v[2] = f2bf(x0.z); v[3] = f2bf(x0.w);
                v[4] = f2bf(x1.x); v[5] = f2bf(x1.y); v[6] = f2bf(x1.z); v[7] = f2bf(x1.w);
                *(short8*)&wlds[l][c * 16 + r][0] = v;
            }
        }
    }
    __syncthreads();
    // ---- persistent per-thread state ----
    float bsum[4];
#pragma unroll
    for (int g = 0; g < 4; ++g)
        bsum[g] = P.b_ih1[g * 1024 + colg] + P.b_hh1[g * 1024 + colg];
    float c0r = P.c0in[b2 * 1024 + colg];            // layer-0 cell state
    float c1r = P.c0in[65536 + b2 * 1024 + colg];    // layer-1 cell state

    const int ab = (blk & 7) * 8 + ((blk >> 3) & 7); // XCD-local batch / group
    const int aq = blk >> 6;
    int ep = 0;
    int t = 0;

    // GEMM over one K-half [kbase, kbase+1024): 32 chunks fully prefetched
    // into registers, 4-chain MFMA consume. Returns per-lane f32x4 partial.
    auto gemm_half = [&](const u16* Abase, int layer, int kbase, f32x4 seed) -> f32x4 {
        const u16* ap = Abase + (size_t)(w * 16 + q) * 2048 + kbase + g4 * 8;
        short8 xa[32];
#pragma unroll
        for (int kk = 0; kk < 32; ++kk)
            xa[kk] = *(const short8*)(ap + kk * 32);
        f32x4 a0 = seed, a1 = {}, a2 = {}, a3 = {};
        const int cbs = (kbase >> 3) + g4;
#pragma unroll
        for (int kk = 0; kk < 32; kk += 4) {
            a0 = __builtin_amdgcn_mfma_f32_16x16x32_bf16(
                xa[kk + 0], *(const short8*)&wlds[layer][(cbs + (kk + 0) * 4) * 16 + q][0], a0, 0, 0, 0);
            a1 = __builtin_amdgcn_mfma_f32_16x16x32_bf16(
                xa[kk + 1], *(const short8*)&wlds[layer][(cbs + (kk + 1) * 4) * 16 + q][0], a1, 0, 0, 0);
            a2 = __builtin_amdgcn_mfma_f32_16x16x32_bf16(
                xa[kk + 2], *(const short8*)&wlds[layer][(cbs + (kk + 2) * 4) * 16 + q][0], a2, 0, 0, 0);
            a3 = __builtin_amdgcn_mfma_f32_16x16x32_bf16(
                xa[kk + 3], *(const short8*)&wlds[layer][(cbs + (kk + 3) * 4) * 16 + q][0], a3, 0, 0, 0);
        }
        return (a0 + a1) + (a2 + a3);
    };

    // LSTM phase: K=1024 ctx/h0' half + epilogue adds + cell; h written via
    // LDS pack -> u64 agent relaxed atomic stores (write-through past L2).
    auto lstm_phase = [&](const u16* Abase, int layer, f32x4 seed,
                          float add0, float add1, float add2, float add3,
                          float& creg, u16* dA, u16* dB, float* outp,
                          float* hnO, float* cnO, int doLast) {
        f32x4 g = gemm_half(Abase, layer, 0, seed);
#pragma unroll
        for (int r = 0; r < 4; ++r) sm.gates[w * 16 + g4 * 4 + r][q] = g[r];
        __syncthreads();
        float gi = sm.gates[b2][j2]      + add0;
        float gf = sm.gates[b2][4 + j2]  + add1;
        float gg = sm.gates[b2][8 + j2]  + add2;
        float go = sm.gates[b2][12 + j2] + add3;
        float cnew = sigm(gf) * creg + sigm(gi) * tanhf(gg);
        float hnew = sigm(go) * tanhf(cnew);
        creg = cnew;
        ((u16*)&sm.gates[b2][16])[j2] = f2bf(hnew);
        if (outp) outp[(size_t)(b2 * T_ + t) * H_ + colg] = hnew;
        if (doLast) { hnO[b2 * 1024 + colg] = hnew; cnO[b2 * 1024 + colg] = cnew; }
        __syncthreads();
        if (tid < 64) {
            u64 pk;
            __builtin_memcpy(&pk, (const u16*)&sm.gates[tid][16], 8);
            __hip_atomic_store((u64*)(dA + tid * 2048 + blk * 4), pk,
                               __ATOMIC_RELAXED, __HIP_MEMORY_SCOPE_AGENT);
            if (dB)
                __hip_atomic_store((u64*)(dB + tid * 2048 + blk * 4), pk,
                                   __ATOMIC_RELAXED, __HIP_MEMORY_SCOPE_AGENT);
        }
    };

    // bootstrap: h0-half seed for step-0 layer 0 (init_state data, visible)
    f32x4 g0p = gemm_half(P.XA0, 0, 1024, f32x4{});
    f32x4 g1p = {};

    for (t = 0; t < T_; ++t) {
        const int last = (t == T_ - 1);
        // rotated exchange buffers (each address written once before read)
        u16* xa0c = P.XA0 + (size_t)t * 131072;        // [ctx_t | h0_{t-1}]
        u16* xa0n = P.XA0 + (size_t)(t + 1) * 131072;
        u16* xa1c = P.XA1 + (size_t)t * 131072;        // [h0'_t | h1_{t-1}]
        u16* xa1n = P.XA1 + (size_t)(t + 1) * 131072;

        // ========== phase 1: attention =====================================
        for (int i = tid; i < H_; i += 256)
            sm.at.h1f[(i >> 8) * 264 + (i & 255)] = bf2f(xa1c[ab * 2048 + 1024 + i]);
        __syncthreads();
        if (tid < 192) {
            int s = tid >> 2, kq = tid & 3;
            const u16* ew = P.encW + ((size_t)ab * S_ + s) * H_ + kq * 256;
            const float2* hp = (const float2*)(sm.at.h1f + kq * 264);
            float p0 = 0.f, p1 = 0.f, p2 = 0.f, p3 = 0.f;
#pragma unroll
            for (int k = 0; k < 256; k += 32) {
                short8 v0 = *(const short8*)(ew + k);
                short8 v1 = *(const short8*)(ew + k + 8);
                short8 v2 = *(const short8*)(ew + k + 16);
                short8 v3 = *(const short8*)(ew + k + 24);
#pragma unroll
                for (int e = 0; e < 8; e += 2) {
                    float2 h0v = hp[(k >> 1) + (e >> 1)];
                    p0 += h0v.x * bf2f(((u16*)&v0)[e]) + h0v.y * bf2f(((u16*)&v0)[e + 1]);
                    float2 h1v = hp[(k >> 1) + 4 + (e >> 1)];
                    p1 += h1v.x * bf2f(((u16*)&v1)[e]) + h1v.y * bf2f(((u16*)&v1)[e + 1]);
                    float2 h2v = hp[(k >> 1) + 8 + (e >> 1)];
                    p2 += h2v.x * bf2f(((u16*)&v2)[e]) + h2v.y * bf2f(((u16*)&v2)[e + 1]);
                    float2 h3v = hp[(k >> 1) + 12 + (e >> 1)];
                    p3 += h3v.x * bf2f(((u16*)&v3)[e]) + h3v.y * bf2f(((u16*)&v3)[e + 1]);
                }
            }
            sm.at.sc[s][kq] = (p0 + p1) + (p2 + p3);
        }
        __syncthreads();
        if (tid < 64) {
            float v = -3.0e38f;
            if (tid < S_) {
                v = sm.at.sc[tid][0] + sm.at.sc[tid][1] + sm.at.sc[tid][2]
                  + sm.at.sc[tid][3] + P.sbias[ab * S_ + tid];
                if (P.mask[ab * S_ + tid]) v = -3.0e38f;
            }
            float mx = v;
            for (int o = 32; o; o >>= 1) mx = fmaxf(mx, __shfl_xor(mx, o));
            float e = (tid < S_) ? __expf(v - mx) : 0.f;
            float su = e;
            for (int o = 32; o; o >>= 1) su += __shfl_xor(su, o);
            if (tid < S_) sm.at.pr[tid] = e / su;
        }
        __syncthreads();
        // PV: ctx columns aq*256 + tid; pair lanes -> u32 write-through store
        {
            int col = aq * 256 + tid;
            const u16* eb = P.encB + (size_t)ab * S_ * H_ + col;
            float a0 = 0.f, a1 = 0.f, a2 = 0.f, a3 = 0.f;
#pragma unroll
            for (int s = 0; s < 48; s += 4) {
                a0 += sm.at.pr[s + 0] * bf2f(eb[(size_t)(s + 0) * H_]);
                a1 += sm.at.pr[s + 1] * bf2f(eb[(size_t)(s + 1) * H_]);
                a2 += sm.at.pr[s + 2] * bf2f(eb[(size_t)(s + 2) * H_]);
                a3 += sm.at.pr[s + 3] * bf2f(eb[(size_t)(s + 3) * H_]);
            }
            u16 myb = f2bf((a0 + a1) + (a2 + a3));
            int other = __shfl_xor((int)myb, 1);
            if ((tid & 1) == 0) {
                unsigned pk = (unsigned)myb | ((unsigned)(u16)other << 16);
                __hip_atomic_store((unsigned*)(xa0c + ab * 2048 + col), pk,
                                   __ATOMIC_RELAXED, __HIP_MEMORY_SCOPE_AGENT);
            }
        }
        gridarrive(P.cnt, P.gcnt, ++ep, ab);
        // shadow of bar1: preG epilogue loads + h1_{t-1} K-half GEMM for L1
        // (xa1c upper: exchanged at bar3(t-1); phase-1 writers touch xa0c
        // lower only -> disjoint)
        const u16* pgp = P.preG + ((size_t)t * 64 + b2) * 4096 + colg;
        u16 pg0 = pgp[0], pg1 = pgp[1024], pg2 = pgp[2048], pg3 = pgp[3072];
        g1p = gemm_half(xa1c, 1, 1024, f32x4{});
        gridpoll(P.gcnt, ep);

        // ========== phase 2: layer 0 (ctx half, K=1024) =====================
        lstm_phase(xa0c, 0, g0p, bf2f(pg0), bf2f(pg1), bf2f(pg2), bf2f(pg3),
                   c0r, xa1c, xa0n + 1024, nullptr, P.hn0, P.cn0, last);
        gridarrive(P.cnt, P.gcnt, ++ep, ab);
        gridpoll(P.gcnt, ep);

        // ========== phase 3: layer 1 (h0' half, K=1024) =====================
        lstm_phase(xa1c, 1, g1p, bsum[0], bsum[1], bsum[2], bsum[3],
                   c1r, xa1n + 1024, nullptr, P.out, P.hn1, P.cn1, last);
        gridarrive(P.cnt, P.gcnt, ++ep, ab);
        // shadow of bar3: next step's h0-half seed (xa0n upper: h0'_t
        // exchanged at bar2; next phase-1 writes xa0n lower only -> disjoint)
        g0p = gemm_half(xa0n, 0, 1024, f32x4{});
        gridpoll(P.gcnt, ep);
    }
}

// ---------------------------------------------------------------------------

extern "C" void kernel_launch(void* const* d_in, const int* in_sizes, int n_in,
                              void* d_out, int out_size, void* d_ws, size_t ws_size,
                              hipStream_t stream) {
    const int*   tgt      = (const int*)d_in[0];
    const float* h0       = (const float*)d_in[1];
    const float* c0in     = (const float*)d_in[2];
    const float* enc      = (const float*)d_in[3];
    const unsigned char* mask = (const unsigned char*)d_in[4];
    const float* embedding= (const float*)d_in[5];
    const float* W_l      = (const float*)d_in[6];
    const float* b_l      = (const float*)d_in[7];
    const float* W_ih0    = (const float*)d_in[8];
    const float* W_hh0    = (const float*)d_in[9];
    const float* b_ih0    = (const float*)d_in[10];
    const float* b_hh0    = (const float*)d_in[11];
    const float* W_ih1    = (const float*)d_in[12];
    const float* W_hh1    = (const float*)d_in[13];
    const float* b_ih1    = (const float*)d_in[14];
    const float* b_hh1    = (const float*)d_in[15];
    float* out = (float*)d_out;

    char* ws = (char*)d_ws;
    u16* W0emb = (u16*)ws;               ws += (size_t)4096 * 512 * 2;
    u16* WlT   = (u16*)ws;               ws += (size_t)1024 * 1024 * 2;
    u16* embA  = (u16*)ws;               ws += (size_t)3072 * 512 * 2;
    u16* encB  = (u16*)ws;               ws += (size_t)3072 * 1024 * 2;
    u16* encWb = (u16*)ws;               ws += (size_t)3072 * 1024 * 2;
    float* sbias = (float*)ws;           ws += (size_t)3072 * 4;
    u16* preG  = (u16*)ws;               ws += (size_t)3072 * 4096 * 2;
    u16* XA0   = (u16*)ws;               ws += (size_t)49 * 131072 * 2;   // rotated
    u16* XA1   = (u16*)ws;               ws += (size_t)49 * 131072 * 2;   // rotated
    unsigned* bar = (unsigned*)ws;       ws += 262144;                    // cnt+gcnt

    // ---- one-time (per launch) setup ----
    cast_copy<<<2048, 256, 0, stream>>>(W0emb, 512, 0, W_ih0, 1536, 0, 4096, 9);
    cast_copy<<<2048, 256, 0, stream>>>(encB, 1024, 0, enc, 1024, 0, 3072, 10);
    transpose_cast<<<4096, 256, 0, stream>>>(WlT, W_l);
    embed_gather<<<3072, 256, 0, stream>>>(embA, embedding, tgt);
    init_state<<<512, 256, 0, stream>>>(XA0, XA1, h0);
    sbias_kernel<<<3072, 64, 0, stream>>>(sbias, enc, b_l);
    gemm64<<<dim3(64, 48), 256, 0, stream>>>(embA, W0emb, preG, b_ih0, b_hh0, 4096, 512);
    gemm64<<<dim3(16, 48), 256, 0, stream>>>(encB, WlT, encWb, nullptr, nullptr, 1024, 1024);
    hipMemsetAsync(bar, 0, 262144, stream);

    PParams prm;
    prm.W_ih0 = W_ih0; prm.W_hh0 = W_hh0; prm.W_ih1 = W_ih1; prm.W_hh1 = W_hh1;
    prm.preG = preG; prm.encW = encWb; prm.encB = encB;
    prm.sbias = sbias; prm.b_ih1 = b_ih1; prm.b_hh1 = b_hh1; prm.c0in = c0in;
    prm.mask = mask;
    prm.XA0 = XA0; prm.XA1 = XA1;
    prm.out = out;
    prm.hn0 = out + 3145728; prm.hn1 = out + 3145728 + 65536;
    prm.cn0 = out + 3276800; prm.cn1 = out + 3276800 + 65536;
    prm.cnt = bar; prm.gcnt = bar + 16384;
    decoder_persistent<<<256, 256, 0, stream>>>(prm);

    (void)in_sizes; (void)n_in; (void)out_size; (void)ws_size;
}

// Round 13
// 1373.655 us; speedup vs baseline: 1.0791x; 1.0791x over previous
//
#include <hip/hip_runtime.h>
#include <stdint.h>

// ---------------------------------------------------------------------------
// Seq2seq decoder: Luong attention + 2-layer LSTM, B=64, T=48, S=48, E=512,
// H=1024. Round 13: round-11 kernel (best passing) with a 2-leg barrier:
// arrivals into 64 quartet counters (unchanged), but every block's wave0
// polls the 64 counters DIRECTLY with a throttled ballot loop
// (s_sleep(16) between rounds, ~0.4us) -- no combiner, no flag legs.
// Throttling keeps poll traffic from queueing ahead of arrival RMWs
// (the r9/r12 failure mode).
// ---------------------------------------------------------------------------

using short8 = __attribute__((ext_vector_type(8))) short;
using f32x4  = __attribute__((ext_vector_type(4))) float;
typedef unsigned short u16;
typedef unsigned long long u64;

#define B_  64
#define T_  48
#define S_  48
#define H_  1024
#define E_  512

__device__ __forceinline__ float bf2f(u16 u) {
    union { unsigned int i; float f; } v; v.i = ((unsigned int)u) << 16; return v.f;
}
__device__ __forceinline__ u16 f2bf(float f) {
    union { float f; unsigned int i; } v; v.f = f;
    unsigned int r = v.i + 0x7fff + ((v.i >> 16) & 1);   // RNE
    return (u16)(r >> 16);
}
__device__ __forceinline__ float sigm(float x) { return 1.f / (1.f + __expf(-x)); }

// ---------------- setup kernels ----------------

__global__ void cast_copy(u16* __restrict__ dst, int dld, int doff,
                          const float* __restrict__ src, int sld, int soff,
                          int rows, int colshift) {
    int cols = 1 << colshift;
    int total = rows << colshift;
    for (int i = blockIdx.x * blockDim.x + threadIdx.x; i < total;
         i += gridDim.x * blockDim.x) {
        int r = i >> colshift, c = i & (cols - 1);
        dst[(size_t)r * dld + doff + c] = f2bf(src[(size_t)r * sld + soff + c]);
    }
}

__global__ void transpose_cast(u16* __restrict__ dst, const float* __restrict__ src) {
    int idx = blockIdx.x * blockDim.x + threadIdx.x;   // 1M threads exactly
    int r = idx >> 10, c = idx & 1023;
    dst[idx] = f2bf(src[(size_t)c * 1024 + r]);
}

__global__ void embed_gather(u16* __restrict__ embA, const float* __restrict__ emb,
                             const int* __restrict__ tgt) {
    int row = blockIdx.x;              // t*64 + b
    int t = row >> 6, b = row & 63;
    int id = tgt[b * T_ + t];
    const float* s = emb + (size_t)id * E_;
    u16* d = embA + (size_t)row * E_;
    for (int e = threadIdx.x; e < E_; e += blockDim.x) d[e] = f2bf(s[e]);
}

__global__ void sbias_kernel(float* __restrict__ sbias, const float* __restrict__ enc,
                             const float* __restrict__ b_l) {
    int r = blockIdx.x, lane = threadIdx.x;
    const float* e = enc + (size_t)r * H_;
    float acc = 0.f;
    for (int k = lane; k < H_; k += 64) acc += b_l[k] * e[k];
    for (int o = 32; o; o >>= 1) acc += __shfl_xor(acc, o);
    if (lane == 0) sbias[r] = acc;
}

__global__ void init_state(u16* __restrict__ xa0_0, u16* __restrict__ xa1_0,
                           const float* __restrict__ h0) {
    int i = blockIdx.x * blockDim.x + threadIdx.x;   // 131072 exactly
    int l = i >> 16, rem = i & 65535, b = rem >> 10, c = rem & 1023;
    u16 hb = f2bf(h0[i]);
    if (l == 0) xa0_0[b * 2048 + 1024 + c] = hb;
    else        xa1_0[b * 2048 + 1024 + c] = hb;
}

// ---------------- setup GEMM: D[M][N] = A[M][K] * W[N][K]^T + bias ----------
__global__ __launch_bounds__(256) void gemm64(
    const u16* __restrict__ A, const u16* __restrict__ W, u16* __restrict__ D,
    const float* __restrict__ bias1, const float* __restrict__ bias2,
    int N, int Kd)
{
    __shared__ float part[4][64][65];
    int tid = threadIdx.x, w = tid >> 6, lane = tid & 63;
    int hf = lane >> 4, q = lane & 15;
    int n0 = blockIdx.x * 64, m0 = blockIdx.y * 64;
    int ks = Kd >> 2;
    int kb = w * ks + hf * 8;
    const u16* ap = A + (size_t)(m0 + q) * Kd + kb;
    const u16* wp = W + (size_t)(n0 + q) * Kd + kb;
    f32x4 acc[4][4] = {};
    for (int k0 = 0; k0 < ks; k0 += 32) {
        short8 bf[4], af[4];
#pragma unroll
        for (int n = 0; n < 4; ++n) bf[n] = *(const short8*)(wp + (size_t)n * 16 * Kd + k0);
#pragma unroll
        for (int m = 0; m < 4; ++m) af[m] = *(const short8*)(ap + (size_t)m * 16 * Kd + k0);
#pragma unroll
        for (int m = 0; m < 4; ++m)
#pragma unroll
            for (int n = 0; n < 4; ++n)
                acc[m][n] = __builtin_amdgcn_mfma_f32_16x16x32_bf16(af[m], bf[n], acc[m][n], 0, 0, 0);
    }
#pragma unroll
    for (int m = 0; m < 4; ++m)
#pragma unroll
        for (int n = 0; n < 4; ++n)
#pragma unroll
            for (int r = 0; r < 4; ++r)
                part[w][m * 16 + hf * 4 + r][n * 16 + q] = acc[m][n][r];
    __syncthreads();
#pragma unroll
    for (int k = 0; k < 16; ++k) {
        int o = tid + k * 256;
        int row = o >> 6, col = o & 63;
        float v = part[0][row][col] + part[1][row][col]
                + part[2][row][col] + part[3][row][col];
        if (bias1) v += bias1[n0 + col] + bias2[n0 + col];
        D[(size_t)(m0 + row) * N + n0 + col] = f2bf(v);
    }
}

// ---------------- persistent decoder kernel ---------------------------------

struct PParams {
    const float *W_ih0, *W_hh0, *W_ih1, *W_hh1;   // f32 weight sources
    const u16  *preG, *encW, *encB;
    const float *sbias, *b_ih1, *b_hh1, *c0in;
    const unsigned char* mask;
    u16 *XA0, *XA1;                               // 49 rotated buffers each
    float *out, *hn0, *hn1, *cn0, *cn1;
    unsigned *cnt;                                // 64 x 256 epoch counters
};

// 2-leg barrier. Arrival: RELAXED agent fetch_add into one of 64 quartet
// counters (4 same-XCD blocks each). Wait: every block's wave0 polls all 64
// counters lane-parallel with ballot, THROTTLED by s_sleep(16) (~0.4us)
// between rounds so poll traffic never queues ahead of arrival RMWs.
// No combiner, no flags, no wbl2 anywhere. Data freshness: write-through
// atomic stores + rotated single-writer buffers. Timeout valve: wrong
// answer, never a hang.
__device__ __forceinline__ void gridarrive(unsigned* cnt, int ep, int g) {
    __syncthreads();                  // drains vmcnt: exchange stores acked
    if (threadIdx.x == 0)
        __hip_atomic_fetch_add(&cnt[g * 256 + ep], 1u,
                               __ATOMIC_RELAXED, __HIP_MEMORY_SCOPE_AGENT);
    asm volatile("" ::: "memory");
}
__device__ __forceinline__ void gridpoll(unsigned* cnt, int ep) {
    if (threadIdx.x < 64) {
        int spin = 0;
        for (;;) {
            unsigned v = __hip_atomic_load(&cnt[threadIdx.x * 256 + ep],
                                           __ATOMIC_RELAXED,
                                           __HIP_MEMORY_SCOPE_AGENT);
            if (__ballot(v >= 4u) == ~0ull) break;
            __builtin_amdgcn_s_sleep(16);
            if (++spin > (1 << 17)) break;
        }
    }
    asm volatile("" ::: "memory");
    __syncthreads();
}

__global__ void __launch_bounds__(256, 1) decoder_persistent(PParams P) {
    // 128 KB resident weights: [layer][chunk*16 + qslot][8] bf16.
    __shared__ u16 wlds[2][4096][8];
    __shared__ union {
        struct { float h1f[1056]; float sc[48][4]; float pr[48]; } at;  // padded
        float gates[64][20];   // cols 0..15 gate partials, 16..17 = h-pack
    } sm;

    const int tid = threadIdx.x, blk = blockIdx.x;
    const int w = tid >> 6, lane = tid & 63, g4 = lane >> 4, q = lane & 15;
    const int b2 = tid >> 2, j2 = tid & 3;
    const int colg = blk * 4 + j2;                 // this thread's h-column

    // ---- one-time: fill LDS weight slices (f32 -> bf16, chunked layout) ----
    {
        int r = tid & 15, cb = tid >> 4;
        int grow = (r >> 2) * 1024 + blk * 4 + (r & 3);   // gate row
#pragma unroll
        for (int l = 0; l < 2; ++l) {
            const float* Sa = l ? P.W_ih1 : P.W_ih0;
            const float* Sb = l ? P.W_hh1 : P.W_hh0;
            int sld  = l ? 1024 : 1536;
            int soff = l ? 0 : 512;
            for (int it = 0; it < 16; ++it) {
                int c = cb + it * 16;
                int k = c * 8;
                const float* src = (k < 1024)
                    ? (Sa + (size_t)grow * sld + soff + k)
                    : (Sb + (size_t)grow * 1024 + (k - 1024));
                float4 x0 = *(const float4*)(src);
                float4 x1 = *(const float4*)(src + 4);
                short8 v;
                v[0] = f2bf(x0.x); v[1] = f2bf(x0.y); v[2] = f2bf(x0.z); v[3] = f2bf(x0.w);
                v[4] = f2bf(x1.x); v[5] = f2bf(x1.y); v[6] = f2bf(x1.z); v[7] = f2bf(x1.w);
                *(short8*)&wlds[l][c * 16 + r][0] = v;
            }
        }
    }
    __syncthreads();
    // ---- persistent per-thread state ----
    float bsum[4];
#pragma unroll
    for (int g = 0; g < 4; ++g)
        bsum[g] = P.b_ih1[g * 1024 + colg] + P.b_hh1[g * 1024 + colg];
    float c0r = P.c0in[b2 * 1024 + colg];            // layer-0 cell state
    float c1r = P.c0in[65536 + b2 * 1024 + colg];    // layer-1 cell state

    const int ab = (blk & 7) * 8 + ((blk >> 3) & 7); // XCD-local batch / group
    const int aq = blk >> 6;
    int ep = 0;
    int t = 0;

    // GEMM over one K-half [kbase, kbase+1024): 32 chunks fully prefetched
    // into registers, 4-chain MFMA consume. Returns per-lane f32x4 partial.
    auto gemm_half = [&](const u16* Abase, int layer, int kbase, f32x4 seed) -> f32x4 {
        const u16* ap = Abase + (size_t)(w * 16 + q) * 2048 + kbase + g4 * 8;
        short8 xa[32];
#pragma unroll
        for (int kk = 0; kk < 32; ++kk)
            xa[kk] = *(const short8*)(ap + kk * 32);
        f32x4 a0 = seed, a1 = {}, a2 = {}, a3 = {};
        const int cbs = (kbase >> 3) + g4;
#pragma unroll
        for (int kk = 0; kk < 32; kk += 4) {
            a0 = __builtin_amdgcn_mfma_f32_16x16x32_bf16(
                xa[kk + 0], *(const short8*)&wlds[layer][(cbs + (kk + 0) * 4) * 16 + q][0], a0, 0, 0, 0);
            a1 = __builtin_amdgcn_mfma_f32_16x16x32_bf16(
                xa[kk + 1], *(const short8*)&wlds[layer][(cbs + (kk + 1) * 4) * 16 + q][0], a1, 0, 0, 0);
            a2 = __builtin_amdgcn_mfma_f32_16x16x32_bf16(
                xa[kk + 2], *(const short8*)&wlds[layer][(cbs + (kk + 2) * 4) * 16 + q][0], a2, 0, 0, 0);
            a3 = __builtin_amdgcn_mfma_f32_16x16x32_bf16(
                xa[kk + 3], *(const short8*)&wlds[layer][(cbs + (kk + 3) * 4) * 16 + q][0], a3, 0, 0, 0);
        }
        return (a0 + a1) + (a2 + a3);
    };

    // LSTM phase: K=1024 ctx/h0' half + epilogue adds + cell; h written via
    // LDS pack -> u64 agent relaxed atomic stores (write-through past L2).
    auto lstm_phase = [&](const u16* Abase, int layer, f32x4 seed,
                          float add0, float add1, float add2, float add3,
                          float& creg, u16* dA, u16* dB, float* outp,
                          float* hnO, float* cnO, int doLast) {
        f32x4 g = gemm_half(Abase, layer, 0, seed);
#pragma unroll
        for (int r = 0; r < 4; ++r) sm.gates[w * 16 + g4 * 4 + r][q] = g[r];
        __syncthreads();
        float gi = sm.gates[b2][j2]      + add0;
        float gf = sm.gates[b2][4 + j2]  + add1;
        float gg = sm.gates[b2][8 + j2]  + add2;
        float go = sm.gates[b2][12 + j2] + add3;
        float cnew = sigm(gf) * creg + sigm(gi) * tanhf(gg);
        float hnew = sigm(go) * tanhf(cnew);
        creg = cnew;
        ((u16*)&sm.gates[b2][16])[j2] = f2bf(hnew);
        if (outp) outp[(size_t)(b2 * T_ + t) * H_ + colg] = hnew;
        if (doLast) { hnO[b2 * 1024 + colg] = hnew; cnO[b2 * 1024 + colg] = cnew; }
        __syncthreads();
        if (tid < 64) {
            u64 pk;
            __builtin_memcpy(&pk, (const u16*)&sm.gates[tid][16], 8);
            __hip_atomic_store((u64*)(dA + tid * 2048 + blk * 4), pk,
                               __ATOMIC_RELAXED, __HIP_MEMORY_SCOPE_AGENT);
            if (dB)
                __hip_atomic_store((u64*)(dB + tid * 2048 + blk * 4), pk,
                                   __ATOMIC_RELAXED, __HIP_MEMORY_SCOPE_AGENT);
        }
    };

    // bootstrap: h0-half seed for step-0 layer 0 (init_state data, visible)
    f32x4 g0p = gemm_half(P.XA0, 0, 1024, f32x4{});
    f32x4 g1p = {};

    for (t = 0; t < T_; ++t) {
        const int last = (t == T_ - 1);
        // rotated exchange buffers (each address written once before read)
        u16* xa0c = P.XA0 + (size_t)t * 131072;        // [ctx_t | h0_{t-1}]
        u16* xa0n = P.XA0 + (size_t)(t + 1) * 131072;
        u16* xa1c = P.XA1 + (size_t)t * 131072;        // [h0'_t | h1_{t-1}]
        u16* xa1n = P.XA1 + (size_t)(t + 1) * 131072;

        // ========== phase 1: attention =====================================
        for (int i = tid; i < H_; i += 256)
            sm.at.h1f[(i >> 8) * 264 + (i & 255)] = bf2f(xa1c[ab * 2048 + 1024 + i]);
        __syncthreads();
        if (tid < 192) {
            int s = tid >> 2, kq = tid & 3;
            const u16* ew = P.encW + ((size_t)ab * S_ + s) * H_ + kq * 256;
            const float2* hp = (const float2*)(sm.at.h1f + kq * 264);
            float p0 = 0.f, p1 = 0.f, p2 = 0.f, p3 = 0.f;
#pragma unroll
            for (int k = 0; k < 256; k += 32) {
                short8 v0 = *(const short8*)(ew + k);
                short8 v1 = *(const short8*)(ew + k + 8);
                short8 v2 = *(const short8*)(ew + k + 16);
                short8 v3 = *(const short8*)(ew + k + 24);
#pragma unroll
                for (int e = 0; e < 8; e += 2) {
                    float2 h0v = hp[(k >> 1) + (e >> 1)];
                    p0 += h0v.x * bf2f(((u16*)&v0)[e]) + h0v.y * bf2f(((u16*)&v0)[e + 1]);
                    float2 h1v = hp[(k >> 1) + 4 + (e >> 1)];
                    p1 += h1v.x * bf2f(((u16*)&v1)[e]) + h1v.y * bf2f(((u16*)&v1)[e + 1]);
                    float2 h2v = hp[(k >> 1) + 8 + (e >> 1)];
                    p2 += h2v.x * bf2f(((u16*)&v2)[e]) + h2v.y * bf2f(((u16*)&v2)[e + 1]);
                    float2 h3v = hp[(k >> 1) + 12 + (e >> 1)];
                    p3 += h3v.x * bf2f(((u16*)&v3)[e]) + h3v.y * bf2f(((u16*)&v3)[e + 1]);
                }
            }
            sm.at.sc[s][kq] = (p0 + p1) + (p2 + p3);
        }
        __syncthreads();
        if (tid < 64) {
            float v = -3.0e38f;
            if (tid < S_) {
                v = sm.at.sc[tid][0] + sm.at.sc[tid][1] + sm.at.sc[tid][2]
                  + sm.at.sc[tid][3] + P.sbias[ab * S_ + tid];
                if (P.mask[ab * S_ + tid]) v = -3.0e38f;
            }
            float mx = v;
            for (int o = 32; o; o >>= 1) mx = fmaxf(mx, __shfl_xor(mx, o));
            float e = (tid < S_) ? __expf(v - mx) : 0.f;
            float su = e;
            for (int o = 32; o; o >>= 1) su += __shfl_xor(su, o);
            if (tid < S_) sm.at.pr[tid] = e / su;
        }
        __syncthreads();
        // PV: ctx columns aq*256 + tid; pair lanes -> u32 write-through store
        {
            int col = aq * 256 + tid;
            const u16* eb = P.encB + (size_t)ab * S_ * H_ + col;
            float a0 = 0.f, a1 = 0.f, a2 = 0.f, a3 = 0.f;
#pragma unroll
            for (int s = 0; s < 48; s += 4) {
                a0 += sm.at.pr[s + 0] * bf2f(eb[(size_t)(s + 0) * H_]);
                a1 += sm.at.pr[s + 1] * bf2f(eb[(size_t)(s + 1) * H_]);
                a2 += sm.at.pr[s + 2] * bf2f(eb[(size_t)(s + 2) * H_]);
                a3 += sm.at.pr[s + 3] * bf2f(eb[(size_t)(s + 3) * H_]);
            }
            u16 myb = f2bf((a0 + a1) + (a2 + a3));
            int other = __shfl_xor((int)myb, 1);
            if ((tid & 1) == 0) {
                unsigned pk = (unsigned)myb | ((unsigned)(u16)other << 16);
                __hip_atomic_store((unsigned*)(xa0c + ab * 2048 + col), pk,
                                   __ATOMIC_RELAXED, __HIP_MEMORY_SCOPE_AGENT);
            }
        }
        gridarrive(P.cnt, ++ep, ab);
        // shadow: preG epilogue loads (setup data; latency hides under poll)
        const u16* pgp = P.preG + ((size_t)t * 64 + b2) * 4096 + colg;
        u16 pg0 = pgp[0], pg1 = pgp[1024], pg2 = pgp[2048], pg3 = pgp[3072];
        gridpoll(P.cnt, ep);

        // ========== phase 2: layer 0 (ctx half, K=1024) =====================
        lstm_phase(xa0c, 0, g0p, bf2f(pg0), bf2f(pg1), bf2f(pg2), bf2f(pg3),
                   c0r, xa1c, xa0n + 1024, nullptr, P.hn0, P.cn0, last);
        gridarrive(P.cnt, ++ep, ab);
        // shadow: h1_{t-1} K-half for layer 1 (xa1c upper half: written at
        // step t-1 phase 3, exchanged >= 1 barrier ago; concurrent writers
        // touch xa1c lower / xa1n upper only -> disjoint)
        g1p = gemm_half(xa1c, 1, 1024, f32x4{});
        gridpoll(P.cnt, ep);

        // ========== phase 3: layer 1 (h0' half, K=1024) =====================
        lstm_phase(xa1c, 1, g1p, bsum[0], bsum[1], bsum[2], bsum[3],
                   c1r, xa1n + 1024, nullptr, P.out, P.hn1, P.cn1, last);
        gridarrive(P.cnt, ++ep, ab);
        // shadow: next step's h0-half seed (xa0n upper: h0'_t written phase 2,
        // exchanged at the phase-2 barrier; next phase-1 writes xa0n lower
        // only -> disjoint)
        g0p = gemm_half(xa0n, 0, 1024, f32x4{});
        gridpoll(P.cnt, ep);
    }
}

// ---------------------------------------------------------------------------

extern "C" void kernel_launch(void* const* d_in, const int* in_sizes, int n_in,
                              void* d_out, int out_size, void* d_ws, size_t ws_size,
                              hipStream_t stream) {
    const int*   tgt      = (const int*)d_in[0];
    const float* h0       = (const float*)d_in[1];
    const float* c0in     = (const float*)d_in[2];
    const float* enc      = (const float*)d_in[3];
    const unsigned char* mask = (const unsigned char*)d_in[4];
    const float* embedding= (const float*)d_in[5];
    const float* W_l      = (const float*)d_in[6];
    const float* b_l      = (const float*)d_in[7];
    const float* W_ih0    = (const float*)d_in[8];
    const float* W_hh0    = (const float*)d_in[9];
    const float* b_ih0    = (const float*)d_in[10];
    const float* b_hh0    = (const float*)d_in[11];
    const float* W_ih1    = (const float*)d_in[12];
    const float* W_hh1    = (const float*)d_in[13];
    const float* b_ih1    = (const float*)d_in[14];
    const float* b_hh1    = (const float*)d_in[15];
    float* out = (float*)d_out;

    char* ws = (char*)d_ws;
    u16* W0emb = (u16*)ws;               ws += (size_t)4096 * 512 * 2;
    u16* WlT   = (u16*)ws;               ws += (size_t)1024 * 1024 * 2;
    u16* embA  = (u16*)ws;               ws += (size_t)3072 * 512 * 2;
    u16* encB  = (u16*)ws;               ws += (size_t)3072 * 1024 * 2;
    u16* encWb = (u16*)ws;               ws += (size_t)3072 * 1024 * 2;
    float* sbias = (float*)ws;           ws += (size_t)3072 * 4;
    u16* preG  = (u16*)ws;               ws += (size_t)3072 * 4096 * 2;
    u16* XA0   = (u16*)ws;               ws += (size_t)49 * 131072 * 2;   // rotated
    u16* XA1   = (u16*)ws;               ws += (size_t)49 * 131072 * 2;   // rotated
    unsigned* bar = (unsigned*)ws;       ws += 262144;                    // cnt

    // ---- one-time (per launch) setup ----
    cast_copy<<<2048, 256, 0, stream>>>(W0emb, 512, 0, W_ih0, 1536, 0, 4096, 9);
    cast_copy<<<2048, 256, 0, stream>>>(encB, 1024, 0, enc, 1024, 0, 3072, 10);
    transpose_cast<<<4096, 256, 0, stream>>>(WlT, W_l);
    embed_gather<<<3072, 256, 0, stream>>>(embA, embedding, tgt);
    init_state<<<512, 256, 0, stream>>>(XA0, XA1, h0);
    sbias_kernel<<<3072, 64, 0, stream>>>(sbias, enc, b_l);
    gemm64<<<dim3(64, 48), 256, 0, stream>>>(embA, W0emb, preG, b_ih0, b_hh0, 4096, 512);
    gemm64<<<dim3(16, 48), 256, 0, stream>>>(encB, WlT, encWb, nullptr, nullptr, 1024, 1024);
    hipMemsetAsync(bar, 0, 262144, stream);

    PParams prm;
    prm.W_ih0 = W_ih0; prm.W_hh0 = W_hh0; prm.W_ih1 = W_ih1; prm.W_hh1 = W_hh1;
    prm.preG = preG; prm.encW = encWb; prm.encB = encB;
    prm.sbias = sbias; prm.b_ih1 = b_ih1; prm.b_hh1 = b_hh1; prm.c0in = c0in;
    prm.mask = mask;
    prm.XA0 = XA0; prm.XA1 = XA1;
    prm.out = out;
    prm.hn0 = out + 3145728; prm.hn1 = out + 3145728 + 65536;
    prm.cn0 = out + 3276800; prm.cn1 = out + 3276800 + 65536;
    prm.cnt = bar;
    decoder_persistent<<<256, 256, 0, stream>>>(prm);

    (void)in_sizes; (void)n_in; (void)out_size; (void)ws_size;
}

// Round 14
// 1321.860 us; speedup vs baseline: 1.1214x; 1.0392x over previous
//
#include <hip/hip_runtime.h>
#include <stdint.h>

// ---------------------------------------------------------------------------
// Seq2seq decoder: Luong attention + 2-layer LSTM, B=64, T=48, S=48, E=512,
// H=1024. Round 14: restore round-11 exactly (best passing configuration):
// weights in LDS (128 KB/block), rotated write-through exchange buffers,
// relaxed-only coherence, quartet-counter + block-0 ballot combiner barrier,
// arrive/poll split with shadow work (preG loads, g1p, next-step g0p).
// Six barrier topologies measured R in [6.6, 10] us; this one is minimal.
// Structure is sync-latency-bound: 3 irreducible global rendezvous/step.
// ---------------------------------------------------------------------------

using short8 = __attribute__((ext_vector_type(8))) short;
using f32x4  = __attribute__((ext_vector_type(4))) float;
typedef unsigned short u16;
typedef unsigned long long u64;

#define B_  64
#define T_  48
#define S_  48
#define H_  1024
#define E_  512

__device__ __forceinline__ float bf2f(u16 u) {
    union { unsigned int i; float f; } v; v.i = ((unsigned int)u) << 16; return v.f;
}
__device__ __forceinline__ u16 f2bf(float f) {
    union { float f; unsigned int i; } v; v.f = f;
    unsigned int r = v.i + 0x7fff + ((v.i >> 16) & 1);   // RNE
    return (u16)(r >> 16);
}
__device__ __forceinline__ float sigm(float x) { return 1.f / (1.f + __expf(-x)); }

// ---------------- setup kernels ----------------

__global__ void cast_copy(u16* __restrict__ dst, int dld, int doff,
                          const float* __restrict__ src, int sld, int soff,
                          int rows, int colshift) {
    int cols = 1 << colshift;
    int total = rows << colshift;
    for (int i = blockIdx.x * blockDim.x + threadIdx.x; i < total;
         i += gridDim.x * blockDim.x) {
        int r = i >> colshift, c = i & (cols - 1);
        dst[(size_t)r * dld + doff + c] = f2bf(src[(size_t)r * sld + soff + c]);
    }
}

__global__ void transpose_cast(u16* __restrict__ dst, const float* __restrict__ src) {
    int idx = blockIdx.x * blockDim.x + threadIdx.x;   // 1M threads exactly
    int r = idx >> 10, c = idx & 1023;
    dst[idx] = f2bf(src[(size_t)c * 1024 + r]);
}

__global__ void embed_gather(u16* __restrict__ embA, const float* __restrict__ emb,
                             const int* __restrict__ tgt) {
    int row = blockIdx.x;              // t*64 + b
    int t = row >> 6, b = row & 63;
    int id = tgt[b * T_ + t];
    const float* s = emb + (size_t)id * E_;
    u16* d = embA + (size_t)row * E_;
    for (int e = threadIdx.x; e < E_; e += blockDim.x) d[e] = f2bf(s[e]);
}

__global__ void sbias_kernel(float* __restrict__ sbias, const float* __restrict__ enc,
                             const float* __restrict__ b_l) {
    int r = blockIdx.x, lane = threadIdx.x;
    const float* e = enc + (size_t)r * H_;
    float acc = 0.f;
    for (int k = lane; k < H_; k += 64) acc += b_l[k] * e[k];
    for (int o = 32; o; o >>= 1) acc += __shfl_xor(acc, o);
    if (lane == 0) sbias[r] = acc;
}

__global__ void init_state(u16* __restrict__ xa0_0, u16* __restrict__ xa1_0,
                           const float* __restrict__ h0) {
    int i = blockIdx.x * blockDim.x + threadIdx.x;   // 131072 exactly
    int l = i >> 16, rem = i & 65535, b = rem >> 10, c = rem & 1023;
    u16 hb = f2bf(h0[i]);
    if (l == 0) xa0_0[b * 2048 + 1024 + c] = hb;
    else        xa1_0[b * 2048 + 1024 + c] = hb;
}

// ---------------- setup GEMM: D[M][N] = A[M][K] * W[N][K]^T + bias ----------
__global__ __launch_bounds__(256) void gemm64(
    const u16* __restrict__ A, const u16* __restrict__ W, u16* __restrict__ D,
    const float* __restrict__ bias1, const float* __restrict__ bias2,
    int N, int Kd)
{
    __shared__ float part[4][64][65];
    int tid = threadIdx.x, w = tid >> 6, lane = tid & 63;
    int hf = lane >> 4, q = lane & 15;
    int n0 = blockIdx.x * 64, m0 = blockIdx.y * 64;
    int ks = Kd >> 2;
    int kb = w * ks + hf * 8;
    const u16* ap = A + (size_t)(m0 + q) * Kd + kb;
    const u16* wp = W + (size_t)(n0 + q) * Kd + kb;
    f32x4 acc[4][4] = {};
    for (int k0 = 0; k0 < ks; k0 += 32) {
        short8 bf[4], af[4];
#pragma unroll
        for (int n = 0; n < 4; ++n) bf[n] = *(const short8*)(wp + (size_t)n * 16 * Kd + k0);
#pragma unroll
        for (int m = 0; m < 4; ++m) af[m] = *(const short8*)(ap + (size_t)m * 16 * Kd + k0);
#pragma unroll
        for (int m = 0; m < 4; ++m)
#pragma unroll
            for (int n = 0; n < 4; ++n)
                acc[m][n] = __builtin_amdgcn_mfma_f32_16x16x32_bf16(af[m], bf[n], acc[m][n], 0, 0, 0);
    }
#pragma unroll
    for (int m = 0; m < 4; ++m)
#pragma unroll
        for (int n = 0; n < 4; ++n)
#pragma unroll
            for (int r = 0; r < 4; ++r)
                part[w][m * 16 + hf * 4 + r][n * 16 + q] = acc[m][n][r];
    __syncthreads();
#pragma unroll
    for (int k = 0; k < 16; ++k) {
        int o = tid + k * 256;
        int row = o >> 6, col = o & 63;
        float v = part[0][row][col] + part[1][row][col]
                + part[2][row][col] + part[3][row][col];
        if (bias1) v += bias1[n0 + col] + bias2[n0 + col];
        D[(size_t)(m0 + row) * N + n0 + col] = f2bf(v);
    }
}

// ---------------- persistent decoder kernel ---------------------------------

struct PParams {
    const float *W_ih0, *W_hh0, *W_ih1, *W_hh1;   // f32 weight sources
    const u16  *preG, *encW, *encB;
    const float *sbias, *b_ih1, *b_hh1, *c0in;
    const unsigned char* mask;
    u16 *XA0, *XA1;                               // 49 rotated buffers each
    float *out, *hn0, *hn1, *cn0, *cn1;
    unsigned *cnt, *flags;                        // 64 x 256 epoch arrays
};

// Round-11 barrier: arrive/poll split. Arrival: RELAXED agent fetch_add into
// one of 64 quartet counters (4 same-XCD blocks each). Combiner: block 0
// wave0 busy-polls all 64 counters lane-parallel (ballot), then broadcasts
// 64 spread flag words. Members: thread 0 busy-polls the group flag.
// No wbl2 anywhere; data freshness = write-through stores + rotation.
// Timeout valve: wrong answer, never a hang.
__device__ __forceinline__ void gridarrive(unsigned* cnt, int ep, int g) {
    __syncthreads();                  // drains vmcnt: exchange stores acked
    if (threadIdx.x == 0)
        __hip_atomic_fetch_add(&cnt[g * 256 + ep], 1u,
                               __ATOMIC_RELAXED, __HIP_MEMORY_SCOPE_AGENT);
    asm volatile("" ::: "memory");
}
__device__ __forceinline__ void gridpoll(unsigned* cnt, unsigned* flags,
                                         int ep, int g) {
    if (blockIdx.x == 0) {
        if (threadIdx.x < 64) {
            int spin = 0;
            for (;;) {
                unsigned v = __hip_atomic_load(&cnt[threadIdx.x * 256 + ep],
                                               __ATOMIC_RELAXED,
                                               __HIP_MEMORY_SCOPE_AGENT);
                if (__ballot(v >= 4u) == ~0ull) break;
                if (++spin > (1 << 20)) break;
            }
            __hip_atomic_store(&flags[threadIdx.x * 256 + ep], 1u,
                               __ATOMIC_RELAXED, __HIP_MEMORY_SCOPE_AGENT);
        }
    } else if (threadIdx.x == 0) {
        int spin = 0;
        while (!__hip_atomic_load(&flags[g * 256 + ep], __ATOMIC_RELAXED,
                                  __HIP_MEMORY_SCOPE_AGENT)) {
            if (++spin > (1 << 20)) break;
        }
    }
    asm volatile("" ::: "memory");
    __syncthreads();
}

__global__ void __launch_bounds__(256, 1) decoder_persistent(PParams P) {
    // 128 KB resident weights: [layer][chunk*16 + qslot][8] bf16.
    __shared__ u16 wlds[2][4096][8];
    __shared__ union {
        struct { float h1f[1056]; float sc[48][4]; float pr[48]; } at;  // padded
        float gates[64][20];   // cols 0..15 gate partials, 16..17 = h-pack
    } sm;

    const int tid = threadIdx.x, blk = blockIdx.x;
    const int w = tid >> 6, lane = tid & 63, g4 = lane >> 4, q = lane & 15;
    const int b2 = tid >> 2, j2 = tid & 3;
    const int colg = blk * 4 + j2;                 // this thread's h-column

    // ---- one-time: fill LDS weight slices (f32 -> bf16, chunked layout) ----
    {
        int r = tid & 15, cb = tid >> 4;
        int grow = (r >> 2) * 1024 + blk * 4 + (r & 3);   // gate row
#pragma unroll
        for (int l = 0; l < 2; ++l) {
            const float* Sa = l ? P.W_ih1 : P.W_ih0;
            const float* Sb = l ? P.W_hh1 : P.W_hh0;
            int sld  = l ? 1024 : 1536;
            int soff = l ? 0 : 512;
            for (int it = 0; it < 16; ++it) {
                int c = cb + it * 16;
                int k = c * 8;
                const float* src = (k < 1024)
                    ? (Sa + (size_t)grow * sld + soff + k)
                    : (Sb + (size_t)grow * 1024 + (k - 1024));
                float4 x0 = *(const float4*)(src);
                float4 x1 = *(const float4*)(src + 4);
                short8 v;
                v[0] = f2bf(x0.x); v[1] = f2bf(x0.y); v[2] = f2bf(x0.z); v[3] = f2bf(x0.w);
                v[4] = f2bf(x1.x); v[5] = f2bf(x1.y); v[6] = f2bf(x1.z); v[7] = f2bf(x1.w);
                *(short8*)&wlds[l][c * 16 + r][0] = v;
            }
        }
    }
    __syncthreads();
    // ---- persistent per-thread state ----
    float bsum[4];
#pragma unroll
    for (int g = 0; g < 4; ++g)
        bsum[g] = P.b_ih1[g * 1024 + colg] + P.b_hh1[g * 1024 + colg];
    float c0r = P.c0in[b2 * 1024 + colg];            // layer-0 cell state
    float c1r = P.c0in[65536 + b2 * 1024 + colg];    // layer-1 cell state

    const int ab = (blk & 7) * 8 + ((blk >> 3) & 7); // XCD-local batch / group
    const int aq = blk >> 6;
    int ep = 0;
    int t = 0;

    // GEMM over one K-half [kbase, kbase+1024): 32 chunks fully prefetched
    // into registers, 4-chain MFMA consume. Returns per-lane f32x4 partial.
    auto gemm_half = [&](const u16* Abase, int layer, int kbase, f32x4 seed) -> f32x4 {
        const u16* ap = Abase + (size_t)(w * 16 + q) * 2048 + kbase + g4 * 8;
        short8 xa[32];
#pragma unroll
        for (int kk = 0; kk < 32; ++kk)
            xa[kk] = *(const short8*)(ap + kk * 32);
        f32x4 a0 = seed, a1 = {}, a2 = {}, a3 = {};
        const int cbs = (kbase >> 3) + g4;
#pragma unroll
        for (int kk = 0; kk < 32; kk += 4) {
            a0 = __builtin_amdgcn_mfma_f32_16x16x32_bf16(
                xa[kk + 0], *(const short8*)&wlds[layer][(cbs + (kk + 0) * 4) * 16 + q][0], a0, 0, 0, 0);
            a1 = __builtin_amdgcn_mfma_f32_16x16x32_bf16(
                xa[kk + 1], *(const short8*)&wlds[layer][(cbs + (kk + 1) * 4) * 16 + q][0], a1, 0, 0, 0);
            a2 = __builtin_amdgcn_mfma_f32_16x16x32_bf16(
                xa[kk + 2], *(const short8*)&wlds[layer][(cbs + (kk + 2) * 4) * 16 + q][0], a2, 0, 0, 0);
            a3 = __builtin_amdgcn_mfma_f32_16x16x32_bf16(
                xa[kk + 3], *(const short8*)&wlds[layer][(cbs + (kk + 3) * 4) * 16 + q][0], a3, 0, 0, 0);
        }
        return (a0 + a1) + (a2 + a3);
    };

    // LSTM phase: K=1024 ctx/h0' half + epilogue adds + cell; h written via
    // LDS pack -> u64 agent relaxed atomic stores (write-through past L2).
    auto lstm_phase = [&](const u16* Abase, int layer, f32x4 seed,
                          float add0, float add1, float add2, float add3,
                          float& creg, u16* dA, u16* dB, float* outp,
                          float* hnO, float* cnO, int doLast) {
        f32x4 g = gemm_half(Abase, layer, 0, seed);
#pragma unroll
        for (int r = 0; r < 4; ++r) sm.gates[w * 16 + g4 * 4 + r][q] = g[r];
        __syncthreads();
        float gi = sm.gates[b2][j2]      + add0;
        float gf = sm.gates[b2][4 + j2]  + add1;
        float gg = sm.gates[b2][8 + j2]  + add2;
        float go = sm.gates[b2][12 + j2] + add3;
        float cnew = sigm(gf) * creg + sigm(gi) * tanhf(gg);
        float hnew = sigm(go) * tanhf(cnew);
        creg = cnew;
        ((u16*)&sm.gates[b2][16])[j2] = f2bf(hnew);
        if (outp) outp[(size_t)(b2 * T_ + t) * H_ + colg] = hnew;
        if (doLast) { hnO[b2 * 1024 + colg] = hnew; cnO[b2 * 1024 + colg] = cnew; }
        __syncthreads();
        if (tid < 64) {
            u64 pk;
            __builtin_memcpy(&pk, (const u16*)&sm.gates[tid][16], 8);
            __hip_atomic_store((u64*)(dA + tid * 2048 + blk * 4), pk,
                               __ATOMIC_RELAXED, __HIP_MEMORY_SCOPE_AGENT);
            if (dB)
                __hip_atomic_store((u64*)(dB + tid * 2048 + blk * 4), pk,
                                   __ATOMIC_RELAXED, __HIP_MEMORY_SCOPE_AGENT);
        }
    };

    // bootstrap: h0-half seed for step-0 layer 0 (init_state data, visible)
    f32x4 g0p = gemm_half(P.XA0, 0, 1024, f32x4{});
    f32x4 g1p = {};

    for (t = 0; t < T_; ++t) {
        const int last = (t == T_ - 1);
        // rotated exchange buffers (each address written once before read)
        u16* xa0c = P.XA0 + (size_t)t * 131072;        // [ctx_t | h0_{t-1}]
        u16* xa0n = P.XA0 + (size_t)(t + 1) * 131072;
        u16* xa1c = P.XA1 + (size_t)t * 131072;        // [h0'_t | h1_{t-1}]
        u16* xa1n = P.XA1 + (size_t)(t + 1) * 131072;

        // ========== phase 1: attention =====================================
        for (int i = tid; i < H_; i += 256)
            sm.at.h1f[(i >> 8) * 264 + (i & 255)] = bf2f(xa1c[ab * 2048 + 1024 + i]);
        __syncthreads();
        if (tid < 192) {
            int s = tid >> 2, kq = tid & 3;
            const u16* ew = P.encW + ((size_t)ab * S_ + s) * H_ + kq * 256;
            const float2* hp = (const float2*)(sm.at.h1f + kq * 264);
            float p0 = 0.f, p1 = 0.f, p2 = 0.f, p3 = 0.f;
#pragma unroll
            for (int k = 0; k < 256; k += 32) {
                short8 v0 = *(const short8*)(ew + k);
                short8 v1 = *(const short8*)(ew + k + 8);
                short8 v2 = *(const short8*)(ew + k + 16);
                short8 v3 = *(const short8*)(ew + k + 24);
#pragma unroll
                for (int e = 0; e < 8; e += 2) {
                    float2 h0v = hp[(k >> 1) + (e >> 1)];
                    p0 += h0v.x * bf2f(((u16*)&v0)[e]) + h0v.y * bf2f(((u16*)&v0)[e + 1]);
                    float2 h1v = hp[(k >> 1) + 4 + (e >> 1)];
                    p1 += h1v.x * bf2f(((u16*)&v1)[e]) + h1v.y * bf2f(((u16*)&v1)[e + 1]);
                    float2 h2v = hp[(k >> 1) + 8 + (e >> 1)];
                    p2 += h2v.x * bf2f(((u16*)&v2)[e]) + h2v.y * bf2f(((u16*)&v2)[e + 1]);
                    float2 h3v = hp[(k >> 1) + 12 + (e >> 1)];
                    p3 += h3v.x * bf2f(((u16*)&v3)[e]) + h3v.y * bf2f(((u16*)&v3)[e + 1]);
                }
            }
            sm.at.sc[s][kq] = (p0 + p1) + (p2 + p3);
        }
        __syncthreads();
        if (tid < 64) {
            float v = -3.0e38f;
            if (tid < S_) {
                v = sm.at.sc[tid][0] + sm.at.sc[tid][1] + sm.at.sc[tid][2]
                  + sm.at.sc[tid][3] + P.sbias[ab * S_ + tid];
                if (P.mask[ab * S_ + tid]) v = -3.0e38f;
            }
            float mx = v;
            for (int o = 32; o; o >>= 1) mx = fmaxf(mx, __shfl_xor(mx, o));
            float e = (tid < S_) ? __expf(v - mx) : 0.f;
            float su = e;
            for (int o = 32; o; o >>= 1) su += __shfl_xor(su, o);
            if (tid < S_) sm.at.pr[tid] = e / su;
        }
        __syncthreads();
        // PV: ctx columns aq*256 + tid; pair lanes -> u32 write-through store
        {
            int col = aq * 256 + tid;
            const u16* eb = P.encB + (size_t)ab * S_ * H_ + col;
            float a0 = 0.f, a1 = 0.f, a2 = 0.f, a3 = 0.f;
#pragma unroll
            for (int s = 0; s < 48; s += 4) {
                a0 += sm.at.pr[s + 0] * bf2f(eb[(size_t)(s + 0) * H_]);
                a1 += sm.at.pr[s + 1] * bf2f(eb[(size_t)(s + 1) * H_]);
                a2 += sm.at.pr[s + 2] * bf2f(eb[(size_t)(s + 2) * H_]);
                a3 += sm.at.pr[s + 3] * bf2f(eb[(size_t)(s + 3) * H_]);
            }
            u16 myb = f2bf((a0 + a1) + (a2 + a3));
            int other = __shfl_xor((int)myb, 1);
            if ((tid & 1) == 0) {
                unsigned pk = (unsigned)myb | ((unsigned)(u16)other << 16);
                __hip_atomic_store((unsigned*)(xa0c + ab * 2048 + col), pk,
                                   __ATOMIC_RELAXED, __HIP_MEMORY_SCOPE_AGENT);
            }
        }
        gridarrive(P.cnt, ++ep, ab);
        // shadow: preG epilogue loads (setup data; latency hides under poll)
        const u16* pgp = P.preG + ((size_t)t * 64 + b2) * 4096 + colg;
        u16 pg0 = pgp[0], pg1 = pgp[1024], pg2 = pgp[2048], pg3 = pgp[3072];
        gridpoll(P.cnt, P.flags, ep, ab);

        // ========== phase 2: layer 0 (ctx half, K=1024) =====================
        lstm_phase(xa0c, 0, g0p, bf2f(pg0), bf2f(pg1), bf2f(pg2), bf2f(pg3),
                   c0r, xa1c, xa0n + 1024, nullptr, P.hn0, P.cn0, last);
        gridarrive(P.cnt, ++ep, ab);
        // shadow: h1_{t-1} K-half for layer 1 (xa1c upper half: written at
        // step t-1 phase 3, exchanged >= 1 barrier ago; concurrent writers
        // touch xa1c lower / xa1n upper only -> disjoint)
        g1p = gemm_half(xa1c, 1, 1024, f32x4{});
        gridpoll(P.cnt, P.flags, ep, ab);

        // ========== phase 3: layer 1 (h0' half, K=1024) =====================
        lstm_phase(xa1c, 1, g1p, bsum[0], bsum[1], bsum[2], bsum[3],
                   c1r, xa1n + 1024, nullptr, P.out, P.hn1, P.cn1, last);
        gridarrive(P.cnt, ++ep, ab);
        // shadow: next step's h0-half seed (xa0n upper: h0'_t written phase 2,
        // exchanged at the phase-2 barrier; next phase-1 writes xa0n lower
        // only -> disjoint)
        g0p = gemm_half(xa0n, 0, 1024, f32x4{});
        gridpoll(P.cnt, P.flags, ep, ab);
    }
}

// ---------------------------------------------------------------------------

extern "C" void kernel_launch(void* const* d_in, const int* in_sizes, int n_in,
                              void* d_out, int out_size, void* d_ws, size_t ws_size,
                              hipStream_t stream) {
    const int*   tgt      = (const int*)d_in[0];
    const float* h0       = (const float*)d_in[1];
    const float* c0in     = (const float*)d_in[2];
    const float* enc      = (const float*)d_in[3];
    const unsigned char* mask = (const unsigned char*)d_in[4];
    const float* embedding= (const float*)d_in[5];
    const float* W_l      = (const float*)d_in[6];
    const float* b_l      = (const float*)d_in[7];
    const float* W_ih0    = (const float*)d_in[8];
    const float* W_hh0    = (const float*)d_in[9];
    const float* b_ih0    = (const float*)d_in[10];
    const float* b_hh0    = (const float*)d_in[11];
    const float* W_ih1    = (const float*)d_in[12];
    const float* W_hh1    = (const float*)d_in[13];
    const float* b_ih1    = (const float*)d_in[14];
    const float* b_hh1    = (const float*)d_in[15];
    float* out = (float*)d_out;

    char* ws = (char*)d_ws;
    u16* W0emb = (u16*)ws;               ws += (size_t)4096 * 512 * 2;
    u16* WlT   = (u16*)ws;               ws += (size_t)1024 * 1024 * 2;
    u16* embA  = (u16*)ws;               ws += (size_t)3072 * 512 * 2;
    u16* encB  = (u16*)ws;               ws += (size_t)3072 * 1024 * 2;
    u16* encWb = (u16*)ws;               ws += (size_t)3072 * 1024 * 2;
    float* sbias = (float*)ws;           ws += (size_t)3072 * 4;
    u16* preG  = (u16*)ws;               ws += (size_t)3072 * 4096 * 2;
    u16* XA0   = (u16*)ws;               ws += (size_t)49 * 131072 * 2;   // rotated
    u16* XA1   = (u16*)ws;               ws += (size_t)49 * 131072 * 2;   // rotated
    unsigned* bar = (unsigned*)ws;       ws += 262144;                    // cnt+flags

    // ---- one-time (per launch) setup ----
    cast_copy<<<2048, 256, 0, stream>>>(W0emb, 512, 0, W_ih0, 1536, 0, 4096, 9);
    cast_copy<<<2048, 256, 0, stream>>>(encB, 1024, 0, enc, 1024, 0, 3072, 10);
    transpose_cast<<<4096, 256, 0, stream>>>(WlT, W_l);
    embed_gather<<<3072, 256, 0, stream>>>(embA, embedding, tgt);
    init_state<<<512, 256, 0, stream>>>(XA0, XA1, h0);
    sbias_kernel<<<3072, 64, 0, stream>>>(sbias, enc, b_l);
    gemm64<<<dim3(64, 48), 256, 0, stream>>>(embA, W0emb, preG, b_ih0, b_hh0, 4096, 512);
    gemm64<<<dim3(16, 48), 256, 0, stream>>>(encB, WlT, encWb, nullptr, nullptr, 1024, 1024);
    hipMemsetAsync(bar, 0, 262144, stream);

    PParams prm;
    prm.W_ih0 = W_ih0; prm.W_hh0 = W_hh0; prm.W_ih1 = W_ih1; prm.W_hh1 = W_hh1;
    prm.preG = preG; prm.encW = encWb; prm.encB = encB;
    prm.sbias = sbias; prm.b_ih1 = b_ih1; prm.b_hh1 = b_hh1; prm.c0in = c0in;
    prm.mask = mask;
    prm.XA0 = XA0; prm.XA1 = XA1;
    prm.out = out;
    prm.hn0 = out + 3145728; prm.hn1 = out + 3145728 + 65536;
    prm.cn0 = out + 3276800; prm.cn1 = out + 3276800 + 65536;
    prm.cnt = bar; prm.flags = bar + 16384;
    decoder_persistent<<<256, 256, 0, stream>>>(prm);

    (void)in_sizes; (void)n_in; (void)out_size; (void)ws_size;
}